// Round 6
// baseline (10196.616 us; speedup 1.0000x reference)
//
#include <hip/hip_runtime.h>
#include <hip/hip_bf16.h>

// GRU, T=512 B=64 D=512 H=1024.
// Round 6: 64 persistent WGs; each WG owns hidden cols [16g,16g+16) for z, r,
// AND candidate -> z and h stay in registers; s=r*h uses fp32 h master.
// One 32-load coherent batch per phase (single LLC round-trip), x-part GEMM
// hidden inside the coherent-load shadow. Hierarchical 8-line barrier.

typedef __attribute__((ext_vector_type(8))) short bf16x8;
typedef __attribute__((ext_vector_type(4))) float f32x4;

#define NWG 64
#define TSTEPS 512
#define LINES 8
#define WGS_PER_LINE 8

#define AT_LD(p) __hip_atomic_load((p), __ATOMIC_RELAXED, __HIP_MEMORY_SCOPE_AGENT)

static __device__ __forceinline__ float sigmoidf_fast(float x) {
    return 1.0f / (1.0f + __expf(-x));
}

static __device__ __forceinline__ unsigned short float_to_bf16bits(float f) {
    __hip_bfloat16 b = __float2bfloat16(f);
    unsigned short us;
    __builtin_memcpy(&us, &b, 2);
    return us;
}

// coherent 2-byte store (write-through past L2)
static __device__ __forceinline__ void store_coh_u16(void* p, unsigned short v) {
    unsigned vv = v;
    asm volatile("global_store_short %0, %1, off sc0 sc1"
                 :: "v"(p), "v"(vv) : "memory");
}

__global__ __launch_bounds__(256) void k_convert_weights(
    const float* __restrict__ Wz, const float* __restrict__ Wr,
    const float* __restrict__ Wc,
    __hip_bfloat16* __restrict__ Wzr, __hip_bfloat16* __restrict__ Wcb)
{
    const long long NW = 1024LL * 1536LL;
    const long long stride = (long long)gridDim.x * blockDim.x;
    for (long long i = (long long)blockIdx.x * blockDim.x + threadIdx.x;
         i < 3 * NW; i += stride) {
        if (i < NW)            Wzr[i] = __float2bfloat16(Wz[i]);
        else if (i < 2 * NW)   Wzr[i] = __float2bfloat16(Wr[i - NW]);
        else                   Wcb[i - 2 * NW] = __float2bfloat16(Wc[i - 2 * NW]);
    }
}

__global__ __launch_bounds__(256) void k_convert_x(
    const float* __restrict__ x, __hip_bfloat16* __restrict__ xb)
{
    const long long N = 512LL * 64LL * 512LL;
    const long long stride = (long long)gridDim.x * blockDim.x;
    for (long long i = (long long)blockIdx.x * blockDim.x + threadIdx.x;
         i < N; i += stride)
        xb[i] = __float2bfloat16(x[i]);
}

__global__ __launch_bounds__(256) void k_init_h(
    const float* __restrict__ h0, __hip_bfloat16* __restrict__ hb)
{
    int i = blockIdx.x * blockDim.x + threadIdx.x;  // grid covers 64*1024
    hb[i] = __float2bfloat16(h0[i]);
}

// Hierarchical grid barrier: 8 padded counter lines, 8 WGs each.
// gen is global monotone phase number; cumulative per-line target = 8*gen.
// gen==0: no arrival (first wait is trivially satisfied).
static __device__ __forceinline__ void grid_barrier(
    unsigned* flags, int g, int lane, int wave, unsigned gen)
{
    if (gen > 0) {
        asm volatile("s_waitcnt vmcnt(0)" ::: "memory");  // drain wave's stores
        __syncthreads();                                  // all waves drained
        if (threadIdx.x == 0)
            atomicAdd(flags + (g >> 3) * 32, 1u);         // device-scope RMW
    }
    if (wave == 0) {
        const unsigned target = gen * WGS_PER_LINE;
        bool ok;
        do {
            ok = (lane < LINES) ? (AT_LD(flags + lane * 32) >= target) : true;
        } while (__any(!ok));
    }
    __syncthreads();
    asm volatile("" ::: "memory");
}

// Persistent GRU: 64 WGs x 256 threads, 1 WG/CU (144KB LDS).
// WG g owns hidden cols [16g,16g+16) for z, r, c; wave w owns batch [16w,16w+16).
// Per lane: col jcol = 16g + (lane&15); batch rows mb..mb+3, mb = 16w + 4*(lane>>4).
__global__ __launch_bounds__(256) void k_gru_persistent(
    const __hip_bfloat16* __restrict__ xb,   // [512][64][512]
    const float* __restrict__ h0,            // [64][1024]
    __hip_bfloat16* __restrict__ hb_,        // [64][1024] bf16 publish of h
    const __hip_bfloat16* __restrict__ Wzr,  // [2048][1536] Wz rows 0..1023, Wr rows 1024..2047
    const __hip_bfloat16* __restrict__ Wcb,  // [1024][1536]
    const float* __restrict__ bz, const float* __restrict__ br,
    const float* __restrict__ bc,
    __hip_bfloat16* __restrict__ sb_,        // [64][1024] s = r*h (coherent)
    float* __restrict__ out,                 // [512][64][1024]
    unsigned* __restrict__ flags)            // 8 lines x 128B
{
    __shared__ short w1[32 * 1536];  // 96KB: rows 0-15 Wz[16g..], rows 16-31 Wr[16g..]
    __shared__ short w2[16 * 1536];  // 48KB: Wc[16g..]

    short* hb = (short*)hb_;
    short* sb = (short*)sb_;

    const int g = blockIdx.x;
    const int lane = threadIdx.x & 63;
    const int wave = threadIdx.x >> 6;
    const int r15 = lane & 15;
    const int q = lane >> 4;        // 0..3
    const int kk = q << 3;          // per-lane K offset (8 elems)
    const int sw = r15 & 7;         // read-side LDS swizzle

    // ---- stage weight slices into LDS (once), blk^(row&7) swizzle
    for (int c = threadIdx.x; c < 32 * 192; c += 256) {
        int row = c / 192, blk = c % 192;
        int srow = (row < 16) ? (g * 16 + row) : (1024 + g * 16 + row - 16);
        bf16x8 v = *(const bf16x8*)((const short*)Wzr +
                                    (long long)srow * 1536 + blk * 8);
        *(bf16x8*)(w1 + (row * 192 + (blk ^ (row & 7))) * 8) = v;
    }
    for (int c = threadIdx.x; c < 16 * 192; c += 256) {
        int row = c / 192, blk = c % 192;
        bf16x8 v = *(const bf16x8*)((const short*)Wcb +
                                    (long long)(g * 16 + row) * 1536 + blk * 8);
        *(bf16x8*)(w2 + (row * 192 + (blk ^ (row & 7))) * 8) = v;
    }
    __syncthreads();

    // ---- per-lane constants
    const int m0 = wave << 4;            // batch tile base (both phases)
    const int jcol = g * 16 + r15;       // owned hidden col
    const float biasZ = bz[jcol];
    const float biasR = br[jcol];
    const float biasC = bc[jcol];
    const int mb = m0 + (q << 2);        // batch base for the 4 acc rows

    // ---- fp32 h master in registers: hreg[v] = h[mb+v][jcol]
    float hreg[4];
#pragma unroll
    for (int v = 0; v < 4; ++v)
        hreg[v] = h0[(mb + v) * 1024 + jcol];

    for (int t = 0; t < TSTEPS; ++t) {
        const short* xt = (const short*)xb + (long long)t * 64 * 512;

        // ======== barrier: h(t-1) published (arrive for prev phase 2) ========
        grid_barrier(flags, g, lane, wave, 2 * t);

        // ======== Phase 1: z,r gates for cols [16g,16g+16) ========
        float zreg[4];
        {
            // issue the 32 coherent h-fragment loads first (1 LLC round-trip)
            const short* Ah = hb + (m0 + r15) * 1024 + kk;
            bf16x8 fr[32];
#pragma unroll
            for (int i = 0; i < 32; ++i)
                asm volatile("global_load_dwordx4 %0, %1, off sc0 sc1"
                             : "=v"(fr[i]) : "v"(Ah + i * 32));

            // x-part (plain L2 loads) hides inside the coherent-load shadow
            f32x4 accZa = {0.f,0.f,0.f,0.f}, accZb = {0.f,0.f,0.f,0.f};
            f32x4 accRa = {0.f,0.f,0.f,0.f}, accRb = {0.f,0.f,0.f,0.f};
            const short* Ax = xt + (m0 + r15) * 512 + kk;
#pragma unroll
            for (int ki = 0; ki < 16; ++ki) {
                bf16x8 a = *(const bf16x8*)(Ax + ki * 32);
                bf16x8 wz = *(const bf16x8*)(w1 + (r15 * 192 + ((ki * 4 + q) ^ sw)) * 8);
                bf16x8 wr = *(const bf16x8*)(w1 + ((16 + r15) * 192 + ((ki * 4 + q) ^ sw)) * 8);
                if (ki & 1) {
                    accZb = __builtin_amdgcn_mfma_f32_16x16x32_bf16(a, wz, accZb, 0, 0, 0);
                    accRb = __builtin_amdgcn_mfma_f32_16x16x32_bf16(a, wr, accRb, 0, 0, 0);
                } else {
                    accZa = __builtin_amdgcn_mfma_f32_16x16x32_bf16(a, wz, accZa, 0, 0, 0);
                    accRa = __builtin_amdgcn_mfma_f32_16x16x32_bf16(a, wr, accRa, 0, 0, 0);
                }
            }
            asm volatile("s_waitcnt vmcnt(0)" ::: "memory");
            __builtin_amdgcn_sched_barrier(0);
#pragma unroll
            for (int i = 0; i < 32; ++i) {
                int ki = 16 + i;
                bf16x8 wz = *(const bf16x8*)(w1 + (r15 * 192 + ((ki * 4 + q) ^ sw)) * 8);
                bf16x8 wr = *(const bf16x8*)(w1 + ((16 + r15) * 192 + ((ki * 4 + q) ^ sw)) * 8);
                if (i & 1) {
                    accZb = __builtin_amdgcn_mfma_f32_16x16x32_bf16(fr[i], wz, accZb, 0, 0, 0);
                    accRb = __builtin_amdgcn_mfma_f32_16x16x32_bf16(fr[i], wr, accRb, 0, 0, 0);
                } else {
                    accZa = __builtin_amdgcn_mfma_f32_16x16x32_bf16(fr[i], wz, accZa, 0, 0, 0);
                    accRa = __builtin_amdgcn_mfma_f32_16x16x32_bf16(fr[i], wr, accRa, 0, 0, 0);
                }
            }
            f32x4 accZ = accZa + accZb;
            f32x4 accR = accRa + accRb;
#pragma unroll
            for (int v = 0; v < 4; ++v) {
                zreg[v] = sigmoidf_fast(accZ[v] + biasZ);
                float rg = sigmoidf_fast(accR[v] + biasR);
                store_coh_u16(sb + (mb + v) * 1024 + jcol,
                              float_to_bf16bits(rg * hreg[v]));  // fp32 h
            }
        }
        grid_barrier(flags, g, lane, wave, 2 * t + 1);  // s published

        // ======== Phase 2: candidate + blend ========
        {
            const short* As = sb + (m0 + r15) * 1024 + kk;
            bf16x8 fs[32];
#pragma unroll
            for (int i = 0; i < 32; ++i)
                asm volatile("global_load_dwordx4 %0, %1, off sc0 sc1"
                             : "=v"(fs[i]) : "v"(As + i * 32));

            f32x4 accCa = {0.f,0.f,0.f,0.f}, accCb = {0.f,0.f,0.f,0.f};
            const short* Ax = xt + (m0 + r15) * 512 + kk;
#pragma unroll
            for (int ki = 0; ki < 16; ++ki) {
                bf16x8 a = *(const bf16x8*)(Ax + ki * 32);
                bf16x8 wc = *(const bf16x8*)(w2 + (r15 * 192 + ((ki * 4 + q) ^ sw)) * 8);
                if (ki & 1)
                    accCb = __builtin_amdgcn_mfma_f32_16x16x32_bf16(a, wc, accCb, 0, 0, 0);
                else
                    accCa = __builtin_amdgcn_mfma_f32_16x16x32_bf16(a, wc, accCa, 0, 0, 0);
            }
            asm volatile("s_waitcnt vmcnt(0)" ::: "memory");
            __builtin_amdgcn_sched_barrier(0);
#pragma unroll
            for (int i = 0; i < 32; ++i) {
                int ki = 16 + i;
                bf16x8 wc = *(const bf16x8*)(w2 + (r15 * 192 + ((ki * 4 + q) ^ sw)) * 8);
                if (i & 1)
                    accCb = __builtin_amdgcn_mfma_f32_16x16x32_bf16(fs[i], wc, accCb, 0, 0, 0);
                else
                    accCa = __builtin_amdgcn_mfma_f32_16x16x32_bf16(fs[i], wc, accCa, 0, 0, 0);
            }
            f32x4 accC = accCa + accCb;
            float* outt = out + (long long)t * 64 * 1024;
#pragma unroll
            for (int v = 0; v < 4; ++v) {
                int bm = mb + v;
                float c = tanhf(accC[v] + biasC);
                float h_new = (1.0f - zreg[v]) * hreg[v] + zreg[v] * c;
                outt[bm * 1024 + jcol] = h_new;            // plain store
                hreg[v] = h_new;                           // register master
                store_coh_u16(hb + bm * 1024 + jcol,       // bf16 publish
                              float_to_bf16bits(h_new));
            }
        }
        // arrive for phase 2 happens at the top of the next iteration (gen 2t+2)
    }
}

extern "C" void kernel_launch(void* const* d_in, const int* in_sizes, int n_in,
                              void* d_out, int out_size, void* d_ws, size_t ws_size,
                              hipStream_t stream)
{
    (void)in_sizes; (void)n_in; (void)out_size; (void)ws_size;
    const float* x  = (const float*)d_in[0];
    const float* h0 = (const float*)d_in[1];
    const float* Wz = (const float*)d_in[2];
    const float* bz = (const float*)d_in[3];
    const float* Wr = (const float*)d_in[4];
    const float* br = (const float*)d_in[5];
    const float* Wc = (const float*)d_in[6];
    const float* bc = (const float*)d_in[7];
    float* out = (float*)d_out;

    // ws layout (bytes, 256-aligned): total ~43.3 MB
    char* ws = (char*)d_ws;
    __hip_bfloat16* Wzr = (__hip_bfloat16*)(ws);              // [2048][1536] bf16
    __hip_bfloat16* Wcb = (__hip_bfloat16*)(ws + 6291456);    // [1024][1536] bf16
    __hip_bfloat16* xb  = (__hip_bfloat16*)(ws + 9437184);    // [512][64][512] bf16
    __hip_bfloat16* hb  = (__hip_bfloat16*)(ws + 42991616);   // [64][1024] bf16
    __hip_bfloat16* sb  = (__hip_bfloat16*)(ws + 43122688);   // [64][1024] bf16
    unsigned*    flags  = (unsigned*)(ws + 43253760);         // 8 lines x 128B

    k_convert_weights<<<1024, 256, 0, stream>>>(Wz, Wr, Wc, Wzr, Wcb);
    k_convert_x<<<2048, 256, 0, stream>>>(x, xb);
    k_init_h<<<256, 256, 0, stream>>>(h0, hb);
    (void)hipMemsetAsync(flags, 0, LINES * 32 * sizeof(unsigned), stream);

    k_gru_persistent<<<NWG, 256, 0, stream>>>(
        xb, h0, hb, Wzr, Wcb, bz, br, bc, sb, out, flags);
}

// Round 7
// 8875.613 us; speedup vs baseline: 1.1488x; 1.1488x over previous
//
#include <hip/hip_runtime.h>
#include <hip/hip_bf16.h>

// GRU, T=512 B=64 D=512 H=1024.
// Round 7: 64 persistent WGs (z,r,c cols owned by same WG -> z,h in registers),
// hierarchical 8-line barrier (8 serialized adds/line, parallel lines),
// x-part GEMMs fully consumed BEFORE the wait (overlap + clean vmcnt
// accounting), single 32-load coherent batch per phase, out-stores deferred
// past the arrive. bf16 MFMA, fp32 accumulate, fp32 h master in registers.

typedef __attribute__((ext_vector_type(8))) short bf16x8;
typedef __attribute__((ext_vector_type(4))) float f32x4;

#define NWG 64
#define TSTEPS 512
#define LINES 8
#define WGS_PER_LINE 8

#define AT_LD(p) __hip_atomic_load((p), __ATOMIC_RELAXED, __HIP_MEMORY_SCOPE_AGENT)

static __device__ __forceinline__ float sigmoidf_fast(float x) {
    return 1.0f / (1.0f + __expf(-x));
}

static __device__ __forceinline__ unsigned short float_to_bf16bits(float f) {
    __hip_bfloat16 b = __float2bfloat16(f);
    unsigned short us;
    __builtin_memcpy(&us, &b, 2);
    return us;
}

// coherent 2-byte store (write-through past L2, visible at LLC)
static __device__ __forceinline__ void store_coh_u16(void* p, unsigned short v) {
    unsigned vv = v;
    asm volatile("global_store_short %0, %1, off sc0 sc1"
                 :: "v"(p), "v"(vv) : "memory");
}

__global__ __launch_bounds__(256) void k_convert_weights(
    const float* __restrict__ Wz, const float* __restrict__ Wr,
    const float* __restrict__ Wc,
    __hip_bfloat16* __restrict__ Wzr, __hip_bfloat16* __restrict__ Wcb)
{
    const long long NW = 1024LL * 1536LL;
    const long long stride = (long long)gridDim.x * blockDim.x;
    for (long long i = (long long)blockIdx.x * blockDim.x + threadIdx.x;
         i < 3 * NW; i += stride) {
        if (i < NW)            Wzr[i] = __float2bfloat16(Wz[i]);
        else if (i < 2 * NW)   Wzr[i] = __float2bfloat16(Wr[i - NW]);
        else                   Wcb[i - 2 * NW] = __float2bfloat16(Wc[i - 2 * NW]);
    }
}

__global__ __launch_bounds__(256) void k_convert_x(
    const float* __restrict__ x, __hip_bfloat16* __restrict__ xb)
{
    const long long N = 512LL * 64LL * 512LL;
    const long long stride = (long long)gridDim.x * blockDim.x;
    for (long long i = (long long)blockIdx.x * blockDim.x + threadIdx.x;
         i < N; i += stride)
        xb[i] = __float2bfloat16(x[i]);
}

__global__ __launch_bounds__(256) void k_init_h(
    const float* __restrict__ h0, __hip_bfloat16* __restrict__ hb)
{
    int i = blockIdx.x * blockDim.x + threadIdx.x;  // grid covers 64*1024
    hb[i] = __float2bfloat16(h0[i]);
}

// ---- hierarchical grid barrier: 8 padded lines, 8 WGs each ----
// arrive: drain stores, then one device-scope add to this WG's line.
static __device__ __forceinline__ void bar_arrive(unsigned* flags, int g) {
    asm volatile("s_waitcnt vmcnt(0)" ::: "memory");  // this wave's stores at LLC
    __syncthreads();                                  // all waves drained
    if (threadIdx.x == 0)
        atomicAdd(flags + (g >> 3) * 32, 1u);
}
// wait: wave 0 lanes 0..7 poll the 8 lines; cumulative target = 8*gen.
static __device__ __forceinline__ void bar_wait(
    unsigned* flags, int lane, int wave, unsigned gen)
{
    if (wave == 0) {
        const unsigned target = gen * WGS_PER_LINE;
        bool ok;
        do {
            ok = (lane < LINES) ? (AT_LD(flags + lane * 32) >= target) : true;
        } while (__any(!ok));
    }
    __syncthreads();
    asm volatile("" ::: "memory");
}

// Persistent GRU: 64 WGs x 256 threads, 1 WG/CU (144KB LDS).
// WG g owns hidden cols [16g,16g+16) for z, r, c; wave w owns batch [16w,16w+16).
__global__ __launch_bounds__(256) void k_gru_persistent(
    const __hip_bfloat16* __restrict__ xb,   // [512][64][512]
    const float* __restrict__ h0,            // [64][1024]
    __hip_bfloat16* __restrict__ hb_,        // [64][1024] bf16 publish of h
    const __hip_bfloat16* __restrict__ Wzr,  // [2048][1536] Wz rows, then Wr rows
    const __hip_bfloat16* __restrict__ Wcb,  // [1024][1536]
    const float* __restrict__ bz, const float* __restrict__ br,
    const float* __restrict__ bc,
    __hip_bfloat16* __restrict__ sb_,        // [64][1024] s = r*h (coherent)
    float* __restrict__ out,                 // [512][64][1024]
    unsigned* __restrict__ flags)            // 8 lines x 128B
{
    __shared__ short w1[32 * 1536];  // 96KB: rows 0-15 Wz[16g..], 16-31 Wr[16g..]
    __shared__ short w2[16 * 1536];  // 48KB: Wc[16g..]

    short* hb = (short*)hb_;
    short* sb = (short*)sb_;

    const int g = blockIdx.x;
    const int lane = threadIdx.x & 63;
    const int wave = threadIdx.x >> 6;
    const int r15 = lane & 15;
    const int q = lane >> 4;        // 0..3
    const int kk = q << 3;          // per-lane K offset (8 elems)
    const int sw = r15 & 7;         // read-side LDS swizzle

    // ---- stage weight slices into LDS (once), blk^(row&7) swizzle
    for (int c = threadIdx.x; c < 32 * 192; c += 256) {
        int row = c / 192, blk = c % 192;
        int srow = (row < 16) ? (g * 16 + row) : (1024 + g * 16 + row - 16);
        bf16x8 v = *(const bf16x8*)((const short*)Wzr +
                                    (long long)srow * 1536 + blk * 8);
        *(bf16x8*)(w1 + (row * 192 + (blk ^ (row & 7))) * 8) = v;
    }
    for (int c = threadIdx.x; c < 16 * 192; c += 256) {
        int row = c / 192, blk = c % 192;
        bf16x8 v = *(const bf16x8*)((const short*)Wcb +
                                    (long long)(g * 16 + row) * 1536 + blk * 8);
        *(bf16x8*)(w2 + (row * 192 + (blk ^ (row & 7))) * 8) = v;
    }
    __syncthreads();

    // ---- per-lane constants
    const int m0 = wave << 4;            // batch tile base
    const int jcol = g * 16 + r15;       // owned hidden col
    const float biasZ = bz[jcol];
    const float biasR = br[jcol];
    const float biasC = bc[jcol];
    const int mb = m0 + (q << 2);        // batch base for the 4 acc rows

    // ---- fp32 h master in registers: hreg[v] = h[mb+v][jcol]
    float hreg[4];
#pragma unroll
    for (int v = 0; v < 4; ++v)
        hreg[v] = h0[(mb + v) * 1024 + jcol];

    for (int t = 0; t < TSTEPS; ++t) {
        const short* xt = (const short*)xb + (long long)t * 64 * 512;
        const short* Ax = xt + (m0 + r15) * 512 + kk;

        // ======== Phase 1 x-part (z,r) — BEFORE the wait, overlaps barrier ====
        f32x4 accZa = {0.f,0.f,0.f,0.f}, accZb = {0.f,0.f,0.f,0.f};
        f32x4 accRa = {0.f,0.f,0.f,0.f}, accRb = {0.f,0.f,0.f,0.f};
#pragma unroll
        for (int ki = 0; ki < 16; ++ki) {
            bf16x8 a = *(const bf16x8*)(Ax + ki * 32);
            bf16x8 wz = *(const bf16x8*)(w1 + (r15 * 192 + ((ki * 4 + q) ^ sw)) * 8);
            bf16x8 wr = *(const bf16x8*)(w1 + ((16 + r15) * 192 + ((ki * 4 + q) ^ sw)) * 8);
            if (ki & 1) {
                accZb = __builtin_amdgcn_mfma_f32_16x16x32_bf16(a, wz, accZb, 0, 0, 0);
                accRb = __builtin_amdgcn_mfma_f32_16x16x32_bf16(a, wr, accRb, 0, 0, 0);
            } else {
                accZa = __builtin_amdgcn_mfma_f32_16x16x32_bf16(a, wz, accZa, 0, 0, 0);
                accRa = __builtin_amdgcn_mfma_f32_16x16x32_bf16(a, wr, accRa, 0, 0, 0);
            }
        }
        __builtin_amdgcn_sched_barrier(0);   // keep all x-loads/MFMAs above
        bar_wait(flags, lane, wave, 2 * t);  // h(t-1) published
        __builtin_amdgcn_sched_barrier(0);

        // ======== Phase 1 h-part: one 32-load coherent batch ========
        float zreg[4];
        {
            const short* Ah = hb + (m0 + r15) * 1024 + kk;
            bf16x8 fr[32];
#pragma unroll
            for (int i = 0; i < 32; ++i)
                asm volatile("global_load_dwordx4 %0, %1, off sc0 sc1"
                             : "=v"(fr[i]) : "v"(Ah + i * 32));
            asm volatile("s_waitcnt vmcnt(0)" ::: "memory");
            __builtin_amdgcn_sched_barrier(0);
#pragma unroll
            for (int i = 0; i < 32; ++i) {
                int ki = 16 + i;
                bf16x8 wz = *(const bf16x8*)(w1 + (r15 * 192 + ((ki * 4 + q) ^ sw)) * 8);
                bf16x8 wr = *(const bf16x8*)(w1 + ((16 + r15) * 192 + ((ki * 4 + q) ^ sw)) * 8);
                if (i & 1) {
                    accZb = __builtin_amdgcn_mfma_f32_16x16x32_bf16(fr[i], wz, accZb, 0, 0, 0);
                    accRb = __builtin_amdgcn_mfma_f32_16x16x32_bf16(fr[i], wr, accRb, 0, 0, 0);
                } else {
                    accZa = __builtin_amdgcn_mfma_f32_16x16x32_bf16(fr[i], wz, accZa, 0, 0, 0);
                    accRa = __builtin_amdgcn_mfma_f32_16x16x32_bf16(fr[i], wr, accRa, 0, 0, 0);
                }
            }
            f32x4 accZ = accZa + accZb;
            f32x4 accR = accRa + accRb;
#pragma unroll
            for (int v = 0; v < 4; ++v) {
                zreg[v] = sigmoidf_fast(accZ[v] + biasZ);
                float rg = sigmoidf_fast(accR[v] + biasR);
                store_coh_u16(sb + (mb + v) * 1024 + jcol,
                              float_to_bf16bits(rg * hreg[v]));  // fp32 h
            }
        }
        bar_arrive(flags, g);                // gen 2t+1

        // ======== Phase 2 x-part — BEFORE the wait ========
        f32x4 accCa = {0.f,0.f,0.f,0.f}, accCb = {0.f,0.f,0.f,0.f};
#pragma unroll
        for (int ki = 0; ki < 16; ++ki) {
            bf16x8 a = *(const bf16x8*)(Ax + ki * 32);
            bf16x8 wc = *(const bf16x8*)(w2 + (r15 * 192 + ((ki * 4 + q) ^ sw)) * 8);
            if (ki & 1)
                accCb = __builtin_amdgcn_mfma_f32_16x16x32_bf16(a, wc, accCb, 0, 0, 0);
            else
                accCa = __builtin_amdgcn_mfma_f32_16x16x32_bf16(a, wc, accCa, 0, 0, 0);
        }
        __builtin_amdgcn_sched_barrier(0);
        bar_wait(flags, lane, wave, 2 * t + 1);  // s published
        __builtin_amdgcn_sched_barrier(0);

        // ======== Phase 2 s-part + blend ========
        {
            const short* As = sb + (m0 + r15) * 1024 + kk;
            bf16x8 fs[32];
#pragma unroll
            for (int i = 0; i < 32; ++i)
                asm volatile("global_load_dwordx4 %0, %1, off sc0 sc1"
                             : "=v"(fs[i]) : "v"(As + i * 32));
            asm volatile("s_waitcnt vmcnt(0)" ::: "memory");
            __builtin_amdgcn_sched_barrier(0);
#pragma unroll
            for (int i = 0; i < 32; ++i) {
                int ki = 16 + i;
                bf16x8 wc = *(const bf16x8*)(w2 + (r15 * 192 + ((ki * 4 + q) ^ sw)) * 8);
                if (i & 1)
                    accCb = __builtin_amdgcn_mfma_f32_16x16x32_bf16(fs[i], wc, accCb, 0, 0, 0);
                else
                    accCa = __builtin_amdgcn_mfma_f32_16x16x32_bf16(fs[i], wc, accCa, 0, 0, 0);
            }
            f32x4 accC = accCa + accCb;
#pragma unroll
            for (int v = 0; v < 4; ++v) {
                float c = tanhf(accC[v] + biasC);
                float h_new = (1.0f - zreg[v]) * hreg[v] + zreg[v] * c;
                hreg[v] = h_new;                           // register master
                store_coh_u16(hb + (mb + v) * 1024 + jcol, // bf16 publish
                              float_to_bf16bits(h_new));
            }
        }
        bar_arrive(flags, g);                // gen 2t+2 (drains hb publishes)

        // deferred HBM output stores — off the synchronization critical path
        {
            float* outt = out + (long long)t * 64 * 1024;
#pragma unroll
            for (int v = 0; v < 4; ++v)
                outt[(mb + v) * 1024 + jcol] = hreg[v];
        }
    }
}

extern "C" void kernel_launch(void* const* d_in, const int* in_sizes, int n_in,
                              void* d_out, int out_size, void* d_ws, size_t ws_size,
                              hipStream_t stream)
{
    (void)in_sizes; (void)n_in; (void)out_size; (void)ws_size;
    const float* x  = (const float*)d_in[0];
    const float* h0 = (const float*)d_in[1];
    const float* Wz = (const float*)d_in[2];
    const float* bz = (const float*)d_in[3];
    const float* Wr = (const float*)d_in[4];
    const float* br = (const float*)d_in[5];
    const float* Wc = (const float*)d_in[6];
    const float* bc = (const float*)d_in[7];
    float* out = (float*)d_out;

    // ws layout (bytes, 256-aligned): total ~43.3 MB
    char* ws = (char*)d_ws;
    __hip_bfloat16* Wzr = (__hip_bfloat16*)(ws);              // [2048][1536] bf16
    __hip_bfloat16* Wcb = (__hip_bfloat16*)(ws + 6291456);    // [1024][1536] bf16
    __hip_bfloat16* xb  = (__hip_bfloat16*)(ws + 9437184);    // [512][64][512] bf16
    __hip_bfloat16* hb  = (__hip_bfloat16*)(ws + 42991616);   // [64][1024] bf16
    __hip_bfloat16* sb  = (__hip_bfloat16*)(ws + 43122688);   // [64][1024] bf16
    unsigned*    flags  = (unsigned*)(ws + 43253760);         // 8 lines x 128B

    k_convert_weights<<<1024, 256, 0, stream>>>(Wz, Wr, Wc, Wzr, Wcb);
    k_convert_x<<<2048, 256, 0, stream>>>(x, xb);
    k_init_h<<<256, 256, 0, stream>>>(h0, hb);
    (void)hipMemsetAsync(flags, 0, LINES * 32 * sizeof(unsigned), stream);

    k_gru_persistent<<<NWG, 256, 0, stream>>>(
        xb, h0, hb, Wzr, Wcb, bz, br, bc, sb, out, flags);
}

// Round 8
// 7483.776 us; speedup vs baseline: 1.3625x; 1.1860x over previous
//
#include <hip/hip_runtime.h>
#include <hip/hip_bf16.h>

// GRU, T=512 B=64 D=512 H=1024.
// Round 8: 128 persistent WGs (one per CU on 128 CUs) = R5's work-spreading +
// R7's register-resident z/h + hierarchical barrier + single coherent batch.
// WG g: cols [16*(g>>1),+16) for z,r,c; batch half (g&1) (32 rows).
// Phase 1: wave 0,1 -> z on batch tiles 0,1; wave 2,3 -> r on tiles 0,1.
// Phase 2: wave 0,1 -> candidate+blend on tiles 0,1 (own z,h in registers).
// s = r*h via WG-local LDS fp32 h tile. bf16 MFMA, fp32 accumulate.

typedef __attribute__((ext_vector_type(8))) short bf16x8;
typedef __attribute__((ext_vector_type(4))) float f32x4;

#define NWG 128
#define TSTEPS 512
#define LINES 16
#define WGS_PER_LINE 8

#define AT_LD(p) __hip_atomic_load((p), __ATOMIC_RELAXED, __HIP_MEMORY_SCOPE_AGENT)

static __device__ __forceinline__ float sigmoidf_fast(float x) {
    return 1.0f / (1.0f + __expf(-x));
}

static __device__ __forceinline__ unsigned short float_to_bf16bits(float f) {
    __hip_bfloat16 b = __float2bfloat16(f);
    unsigned short us;
    __builtin_memcpy(&us, &b, 2);
    return us;
}

// coherent 2-byte store (write-through past L2, visible at LLC)
static __device__ __forceinline__ void store_coh_u16(void* p, unsigned short v) {
    unsigned vv = v;
    asm volatile("global_store_short %0, %1, off sc0 sc1"
                 :: "v"(p), "v"(vv) : "memory");
}

__global__ __launch_bounds__(256) void k_convert_weights(
    const float* __restrict__ Wz, const float* __restrict__ Wr,
    const float* __restrict__ Wc,
    __hip_bfloat16* __restrict__ Wzr, __hip_bfloat16* __restrict__ Wcb)
{
    const long long NW = 1024LL * 1536LL;
    const long long stride = (long long)gridDim.x * blockDim.x;
    for (long long i = (long long)blockIdx.x * blockDim.x + threadIdx.x;
         i < 3 * NW; i += stride) {
        if (i < NW)            Wzr[i] = __float2bfloat16(Wz[i]);
        else if (i < 2 * NW)   Wzr[i] = __float2bfloat16(Wr[i - NW]);
        else                   Wcb[i - 2 * NW] = __float2bfloat16(Wc[i - 2 * NW]);
    }
}

__global__ __launch_bounds__(256) void k_convert_x(
    const float* __restrict__ x, __hip_bfloat16* __restrict__ xb)
{
    const long long N = 512LL * 64LL * 512LL;
    const long long stride = (long long)gridDim.x * blockDim.x;
    for (long long i = (long long)blockIdx.x * blockDim.x + threadIdx.x;
         i < N; i += stride)
        xb[i] = __float2bfloat16(x[i]);
}

__global__ __launch_bounds__(256) void k_init_h(
    const float* __restrict__ h0, __hip_bfloat16* __restrict__ hb)
{
    int i = blockIdx.x * blockDim.x + threadIdx.x;  // grid covers 64*1024
    hb[i] = __float2bfloat16(h0[i]);
}

// ---- hierarchical grid barrier: 16 padded lines, 8 WGs each ----
static __device__ __forceinline__ void bar_arrive(unsigned* flags, int g) {
    asm volatile("s_waitcnt vmcnt(0)" ::: "memory");  // wave's stores at LLC
    __syncthreads();                                  // all waves drained
    if (threadIdx.x == 0)
        atomicAdd(flags + (g >> 3) * 32, 1u);
}
static __device__ __forceinline__ void bar_wait(
    unsigned* flags, int lane, int wave, unsigned gen)
{
    if (wave == 0) {
        const unsigned target = gen * WGS_PER_LINE;
        bool ok;
        do {
            ok = (lane < LINES) ? (AT_LD(flags + lane * 32) >= target) : true;
        } while (__any(!ok));
    }
    __syncthreads();
    asm volatile("" ::: "memory");
}

// Persistent GRU: 128 WGs x 256 threads, 1 WG/CU (146KB LDS).
__global__ __launch_bounds__(256) void k_gru_persistent(
    const __hip_bfloat16* __restrict__ xb,   // [512][64][512]
    const float* __restrict__ h0,            // [64][1024]
    __hip_bfloat16* __restrict__ hb_,        // [64][1024] bf16 publish of h
    const __hip_bfloat16* __restrict__ Wzr,  // [2048][1536] Wz rows, then Wr rows
    const __hip_bfloat16* __restrict__ Wcb,  // [1024][1536]
    const float* __restrict__ bz, const float* __restrict__ br,
    const float* __restrict__ bc,
    __hip_bfloat16* __restrict__ sb_,        // [64][1024] s = r*h (coherent)
    float* __restrict__ out,                 // [512][64][1024]
    unsigned* __restrict__ flags)            // 16 lines x 128B
{
    __shared__ short w1[32 * 1536];   // 96KB: rows 0-15 Wz[c0..], 16-31 Wr[c0..]
    __shared__ short w2[16 * 1536];   // 48KB: Wc[c0..]
    __shared__ float hshare[32 * 17]; // fp32 h tile [32 batch][16 cols], +1 pad

    short* hb = (short*)hb_;
    short* sb = (short*)sb_;

    const int g = blockIdx.x;
    const int lane = threadIdx.x & 63;
    const int wave = threadIdx.x >> 6;
    const int r15 = lane & 15;
    const int q = lane >> 4;        // 0..3
    const int kk = q << 3;          // per-lane K offset (8 elems)
    const int sw = r15 & 7;         // read-side LDS swizzle

    const int c0 = (g >> 1) * 16;        // owned col tile
    const int B0 = (g & 1) * 32;         // owned batch half
    const int mt = B0 + (wave & 1) * 16; // this wave's batch-tile base
    const bool isZ = (wave < 2);         // phase-1 gate role
    const int gb = isZ ? 0 : 16;         // w1 row base for this wave's gate
    const int jcol = c0 + r15;           // owned hidden col

    // ---- stage weight slices into LDS (once), blk^(row&7) swizzle
    for (int c = threadIdx.x; c < 32 * 192; c += 256) {
        int row = c / 192, blk = c % 192;
        int srow = (row < 16) ? (c0 + row) : (1024 + c0 + row - 16);
        bf16x8 v = *(const bf16x8*)((const short*)Wzr +
                                    (long long)srow * 1536 + blk * 8);
        *(bf16x8*)(w1 + (row * 192 + (blk ^ (row & 7))) * 8) = v;
    }
    for (int c = threadIdx.x; c < 16 * 192; c += 256) {
        int row = c / 192, blk = c % 192;
        bf16x8 v = *(const bf16x8*)((const short*)Wcb +
                                    (long long)(c0 + row) * 1536 + blk * 8);
        *(bf16x8*)(w2 + (row * 192 + (blk ^ (row & 7))) * 8) = v;
    }

    const float biasG = isZ ? bz[jcol] : br[jcol];
    const float biasC = bc[jcol];

    // ---- fp32 h master (waves 0,1 own h[mt+qv][jcol]); mirror into hshare
    float hreg[4];
    if (isZ) {
#pragma unroll
        for (int v = 0; v < 4; ++v) {
            hreg[v] = h0[(mt + (q << 2) + v) * 1024 + jcol];
            hshare[((wave & 1) * 16 + (q << 2) + v) * 17 + r15] = hreg[v];
        }
    }
    __syncthreads();

    float zreg[4];

    for (int t = 0; t < TSTEPS; ++t) {
        const short* xt = (const short*)xb + (long long)t * 64 * 512;
        const short* Ax = xt + (mt + r15) * 512 + kk;

        // ==== Phase 1 x-part (gate G = z or r per wave role), pre-wait ====
        f32x4 accA = {0.f,0.f,0.f,0.f}, accB = {0.f,0.f,0.f,0.f};
#pragma unroll
        for (int ki = 0; ki < 16; ++ki) {
            bf16x8 a = *(const bf16x8*)(Ax + ki * 32);
            bf16x8 w = *(const bf16x8*)(w1 + ((gb + r15) * 192 + ((ki * 4 + q) ^ sw)) * 8);
            if (ki & 1) accB = __builtin_amdgcn_mfma_f32_16x16x32_bf16(a, w, accB, 0, 0, 0);
            else        accA = __builtin_amdgcn_mfma_f32_16x16x32_bf16(a, w, accA, 0, 0, 0);
        }
        __builtin_amdgcn_sched_barrier(0);
        bar_wait(flags, lane, wave, 2 * t);   // h(t-1) published
        __builtin_amdgcn_sched_barrier(0);

        // ==== Phase 1 h-part: one 32-load coherent batch ====
        {
            const short* Ah = hb + (mt + r15) * 1024 + kk;
            bf16x8 fr[32];
#pragma unroll
            for (int i = 0; i < 32; ++i)
                asm volatile("global_load_dwordx4 %0, %1, off sc0 sc1"
                             : "=v"(fr[i]) : "v"(Ah + i * 32));
            asm volatile("s_waitcnt vmcnt(0)" ::: "memory");
            __builtin_amdgcn_sched_barrier(0);
#pragma unroll
            for (int i = 0; i < 32; ++i) {
                int ki = 16 + i;
                bf16x8 w = *(const bf16x8*)(w1 + ((gb + r15) * 192 + ((ki * 4 + q) ^ sw)) * 8);
                if (i & 1) accB = __builtin_amdgcn_mfma_f32_16x16x32_bf16(fr[i], w, accB, 0, 0, 0);
                else       accA = __builtin_amdgcn_mfma_f32_16x16x32_bf16(fr[i], w, accA, 0, 0, 0);
            }
            f32x4 acc = accA + accB;
            if (isZ) {       // z gate stays in registers
#pragma unroll
                for (int v = 0; v < 4; ++v)
                    zreg[v] = sigmoidf_fast(acc[v] + biasG);
            } else {         // r gate -> s = r*h (h from WG-local LDS, fp32)
#pragma unroll
                for (int v = 0; v < 4; ++v) {
                    float rg = sigmoidf_fast(acc[v] + biasG);
                    float hv = hshare[((wave & 1) * 16 + (q << 2) + v) * 17 + r15];
                    store_coh_u16(sb + (mt + (q << 2) + v) * 1024 + jcol,
                                  float_to_bf16bits(rg * hv));
                }
            }
        }
        bar_arrive(flags, g);                 // gen 2t+1

        // ==== Phase 2 x-part (candidate), waves 0,1 only, pre-wait ====
        f32x4 accCa = {0.f,0.f,0.f,0.f}, accCb = {0.f,0.f,0.f,0.f};
        if (isZ) {
#pragma unroll
            for (int ki = 0; ki < 16; ++ki) {
                bf16x8 a = *(const bf16x8*)(Ax + ki * 32);
                bf16x8 w = *(const bf16x8*)(w2 + (r15 * 192 + ((ki * 4 + q) ^ sw)) * 8);
                if (ki & 1) accCb = __builtin_amdgcn_mfma_f32_16x16x32_bf16(a, w, accCb, 0, 0, 0);
                else        accCa = __builtin_amdgcn_mfma_f32_16x16x32_bf16(a, w, accCa, 0, 0, 0);
            }
        }
        __builtin_amdgcn_sched_barrier(0);
        bar_wait(flags, lane, wave, 2 * t + 1);  // s published
        __builtin_amdgcn_sched_barrier(0);

        // ==== Phase 2 s-part + blend (waves 0,1) ====
        if (isZ) {
            const short* As = sb + (mt + r15) * 1024 + kk;
            bf16x8 fs[32];
#pragma unroll
            for (int i = 0; i < 32; ++i)
                asm volatile("global_load_dwordx4 %0, %1, off sc0 sc1"
                             : "=v"(fs[i]) : "v"(As + i * 32));
            asm volatile("s_waitcnt vmcnt(0)" ::: "memory");
            __builtin_amdgcn_sched_barrier(0);
#pragma unroll
            for (int i = 0; i < 32; ++i) {
                int ki = 16 + i;
                bf16x8 w = *(const bf16x8*)(w2 + (r15 * 192 + ((ki * 4 + q) ^ sw)) * 8);
                if (i & 1) accCb = __builtin_amdgcn_mfma_f32_16x16x32_bf16(fs[i], w, accCb, 0, 0, 0);
                else       accCa = __builtin_amdgcn_mfma_f32_16x16x32_bf16(fs[i], w, accCa, 0, 0, 0);
            }
            f32x4 accC = accCa + accCb;
#pragma unroll
            for (int v = 0; v < 4; ++v) {
                float c = tanhf(accC[v] + biasC);
                float h_new = (1.0f - zreg[v]) * hreg[v] + zreg[v] * c;
                hreg[v] = h_new;
                hshare[((wave & 1) * 16 + (q << 2) + v) * 17 + r15] = h_new;
                store_coh_u16(hb + (mt + (q << 2) + v) * 1024 + jcol,
                              float_to_bf16bits(h_new));
            }
        }
        bar_arrive(flags, g);                 // gen 2t+2 (drains hb publishes)

        // deferred HBM output stores — off the synchronization critical path
        if (isZ) {
            float* outt = out + (long long)t * 64 * 1024;
#pragma unroll
            for (int v = 0; v < 4; ++v)
                outt[(mt + (q << 2) + v) * 1024 + jcol] = hreg[v];
        }
    }
}

extern "C" void kernel_launch(void* const* d_in, const int* in_sizes, int n_in,
                              void* d_out, int out_size, void* d_ws, size_t ws_size,
                              hipStream_t stream)
{
    (void)in_sizes; (void)n_in; (void)out_size; (void)ws_size;
    const float* x  = (const float*)d_in[0];
    const float* h0 = (const float*)d_in[1];
    const float* Wz = (const float*)d_in[2];
    const float* bz = (const float*)d_in[3];
    const float* Wr = (const float*)d_in[4];
    const float* br = (const float*)d_in[5];
    const float* Wc = (const float*)d_in[6];
    const float* bc = (const float*)d_in[7];
    float* out = (float*)d_out;

    // ws layout (bytes, 256-aligned): total ~43.3 MB
    char* ws = (char*)d_ws;
    __hip_bfloat16* Wzr = (__hip_bfloat16*)(ws);              // [2048][1536] bf16
    __hip_bfloat16* Wcb = (__hip_bfloat16*)(ws + 6291456);    // [1024][1536] bf16
    __hip_bfloat16* xb  = (__hip_bfloat16*)(ws + 9437184);    // [512][64][512] bf16
    __hip_bfloat16* hb  = (__hip_bfloat16*)(ws + 42991616);   // [64][1024] bf16
    __hip_bfloat16* sb  = (__hip_bfloat16*)(ws + 43122688);   // [64][1024] bf16
    unsigned*    flags  = (unsigned*)(ws + 43253760);         // 16 lines x 128B

    k_convert_weights<<<1024, 256, 0, stream>>>(Wz, Wr, Wc, Wzr, Wcb);
    k_convert_x<<<2048, 256, 0, stream>>>(x, xb);
    k_init_h<<<256, 256, 0, stream>>>(h0, hb);
    (void)hipMemsetAsync(flags, 0, LINES * 32 * sizeof(unsigned), stream);

    k_gru_persistent<<<NWG, 256, 0, stream>>>(
        xb, h0, hb, Wzr, Wcb, bz, br, bc, sb, out, flags);
}

// Round 9
// 5212.870 us; speedup vs baseline: 1.9560x; 1.4356x over previous
//
#include <hip/hip_runtime.h>
#include <hip/hip_bf16.h>

// GRU, T=512 B=64 D=512 H=1024.
// Round 9: 128 persistent WGs. Changes vs R8:
//  (1) weight LDS layout transposed to [K-block][row], z/r/c separate arrays
//      -> wave reads 1024 contiguous bytes per ds_read_b128 group: conflict-free.
//  (2) K split across waves (not gates): each wave computes z AND r partials
//      for its K-half -> h fragments fetched once (halves LLC pull), all 4
//      waves active in phase 2; cross-wave LDS f32 reduce.
//  (3) per-WG plain coherent flag stores (no atomic RMW serialization).
// bf16 MFMA, fp32 accumulate, fp32 h master in registers of waves 0,1.

typedef __attribute__((ext_vector_type(8))) short bf16x8;
typedef __attribute__((ext_vector_type(4))) float f32x4;

#define NWG 128
#define TSTEPS 512

#define AT_LD(p) __hip_atomic_load((p), __ATOMIC_RELAXED, __HIP_MEMORY_SCOPE_AGENT)
#define AT_ST(p, v) __hip_atomic_store((p), (v), __ATOMIC_RELAXED, __HIP_MEMORY_SCOPE_AGENT)

static __device__ __forceinline__ float sigmoidf_fast(float x) {
    return 1.0f / (1.0f + __expf(-x));
}

static __device__ __forceinline__ unsigned short float_to_bf16bits(float f) {
    __hip_bfloat16 b = __float2bfloat16(f);
    unsigned short us;
    __builtin_memcpy(&us, &b, 2);
    return us;
}

// coherent 2-byte store (write-through past L2, visible at LLC)
static __device__ __forceinline__ void store_coh_u16(void* p, unsigned short v) {
    unsigned vv = v;
    asm volatile("global_store_short %0, %1, off sc0 sc1"
                 :: "v"(p), "v"(vv) : "memory");
}

__global__ __launch_bounds__(256) void k_convert_weights(
    const float* __restrict__ Wz, const float* __restrict__ Wr,
    const float* __restrict__ Wc,
    __hip_bfloat16* __restrict__ Wzr, __hip_bfloat16* __restrict__ Wcb)
{
    const long long NW = 1024LL * 1536LL;
    const long long stride = (long long)gridDim.x * blockDim.x;
    for (long long i = (long long)blockIdx.x * blockDim.x + threadIdx.x;
         i < 3 * NW; i += stride) {
        if (i < NW)            Wzr[i] = __float2bfloat16(Wz[i]);
        else if (i < 2 * NW)   Wzr[i] = __float2bfloat16(Wr[i - NW]);
        else                   Wcb[i - 2 * NW] = __float2bfloat16(Wc[i - 2 * NW]);
    }
}

__global__ __launch_bounds__(256) void k_convert_x(
    const float* __restrict__ x, __hip_bfloat16* __restrict__ xb)
{
    const long long N = 512LL * 64LL * 512LL;
    const long long stride = (long long)gridDim.x * blockDim.x;
    for (long long i = (long long)blockIdx.x * blockDim.x + threadIdx.x;
         i < N; i += stride)
        xb[i] = __float2bfloat16(x[i]);
}

__global__ __launch_bounds__(256) void k_init_h(
    const float* __restrict__ h0, __hip_bfloat16* __restrict__ hb)
{
    int i = blockIdx.x * blockDim.x + threadIdx.x;  // grid covers 64*1024
    hb[i] = __float2bfloat16(h0[i]);
}

// ---- per-WG flag barrier: 128 flags, one 128B line each ----
static __device__ __forceinline__ void bar_arrive(
    unsigned* flags, int g, unsigned gen)
{
    asm volatile("s_waitcnt vmcnt(0)" ::: "memory");  // wave's stores at LLC
    __syncthreads();                                  // all waves drained
    if (threadIdx.x == 0)
        AT_ST(flags + g * 32, gen);                   // plain coherent store
}
static __device__ __forceinline__ void bar_wait(
    unsigned* flags, int lane, int wave, unsigned gen)
{
    if (wave == 0) {
        const unsigned* f1 = flags + lane * 32;
        const unsigned* f2 = flags + (lane + 64) * 32;
        bool ok;
        do {
            unsigned a = AT_LD(f1);
            unsigned b = AT_LD(f2);
            ok = (a >= gen) & (b >= gen);
        } while (__any(!ok));
    }
    __syncthreads();
    asm volatile("" ::: "memory");
}

// Persistent GRU: 128 WGs x 256 threads, 1 WG/CU (~148KB LDS).
// WG g: cols c0=[16*(g>>1),+16) for z,r,c; batch half B0=(g&1)*32.
// Wave w: batch tile mt=B0+(w&1)*16, K-half kh=w>>1.
// Waves 0,1 hold z and fp32-h state and do epilogues; waves 2,3 contribute
// K-half-1 partials via LDS reduce.
__global__ __launch_bounds__(256) void k_gru_persistent(
    const __hip_bfloat16* __restrict__ xb,   // [512][64][512]
    const float* __restrict__ h0,            // [64][1024]
    __hip_bfloat16* __restrict__ hb_,        // [64][1024] bf16 publish of h
    const __hip_bfloat16* __restrict__ Wzr,  // [2048][1536] Wz rows, then Wr rows
    const __hip_bfloat16* __restrict__ Wcb,  // [1024][1536]
    const float* __restrict__ bz, const float* __restrict__ br,
    const float* __restrict__ bc,
    __hip_bfloat16* __restrict__ sb_,        // [64][1024] s = r*h (coherent)
    float* __restrict__ out,                 // [512][64][1024]
    unsigned* __restrict__ flags)            // 128 x 128B
{
    // Transposed weight slices: [K-block 0..191][row 0..15][8 bf16]
    __shared__ short w1z[192 * 16 * 8];   // 48KB
    __shared__ short w1r[192 * 16 * 8];   // 48KB
    __shared__ short w2c[192 * 16 * 8];   // 48KB
    __shared__ f32x4 red[2][2][64];       // 4KB cross-wave partial buffer

    short* hb = (short*)hb_;
    short* sb = (short*)sb_;

    const int g = blockIdx.x;
    const int lane = threadIdx.x & 63;
    const int wave = threadIdx.x >> 6;
    const int r15 = lane & 15;
    const int q = lane >> 4;        // 0..3
    const int kk = q << 3;          // per-lane K offset within 32-elem block

    const int c0 = (g >> 1) * 16;        // owned col tile
    const int B0 = (g & 1) * 32;         // owned batch half
    const int tile = wave & 1;           // batch tile within half
    const int kh = wave >> 1;            // K-half (0 or 1)
    const int mt = B0 + tile * 16;       // this wave's batch-tile base
    const int jcol = c0 + r15;           // owned hidden col (epilogue)
    const int mb = mt + (q << 2);        // batch base for the 4 acc rows
    const bool owner = (wave < 2);       // epilogue/state-owning waves

    // ---- stage weights transposed: unit index c = blk*16+row (contiguous LDS)
    for (int c = threadIdx.x; c < 192 * 16; c += 256) {
        int row = c & 15, blk = c >> 4;
        bf16x8 vz = *(const bf16x8*)((const short*)Wzr +
                                     (long long)(c0 + row) * 1536 + blk * 8);
        bf16x8 vr = *(const bf16x8*)((const short*)Wzr +
                                     (long long)(1024 + c0 + row) * 1536 + blk * 8);
        bf16x8 vc = *(const bf16x8*)((const short*)Wcb +
                                     (long long)(c0 + row) * 1536 + blk * 8);
        *(bf16x8*)(w1z + c * 8) = vz;
        *(bf16x8*)(w1r + c * 8) = vr;
        *(bf16x8*)(w2c + c * 8) = vc;
    }

    const float biasZ = bz[jcol];
    const float biasR = br[jcol];
    const float biasC = bc[jcol];

    // ---- fp32 h master in registers of waves 0,1
    float hreg[4];
    if (owner) {
#pragma unroll
        for (int v = 0; v < 4; ++v)
            hreg[v] = h0[(mb + v) * 1024 + jcol];
    }
    __syncthreads();

    float zreg[4] = {0.f, 0.f, 0.f, 0.f};

    for (int t = 0; t < TSTEPS; ++t) {
        const short* xt = (const short*)xb + (long long)t * 64 * 512;
        const short* AxW = xt + (mt + r15) * 512 + kh * 256 + kk;

        // ==== Phase 1 x-part (z AND r, this wave's K-half), pre-wait ====
        f32x4 zA = {0.f,0.f,0.f,0.f}, zB = {0.f,0.f,0.f,0.f};
        f32x4 rA = {0.f,0.f,0.f,0.f}, rB = {0.f,0.f,0.f,0.f};
#pragma unroll
        for (int i = 0; i < 8; ++i) {
            bf16x8 a = *(const bf16x8*)(AxW + i * 32);
            int bk = kh * 32 + i * 4 + q;
            bf16x8 wz = *(const bf16x8*)(w1z + (bk * 16 + r15) * 8);
            bf16x8 wr = *(const bf16x8*)(w1r + (bk * 16 + r15) * 8);
            if (i & 1) { zB = __builtin_amdgcn_mfma_f32_16x16x32_bf16(a, wz, zB, 0, 0, 0);
                         rB = __builtin_amdgcn_mfma_f32_16x16x32_bf16(a, wr, rB, 0, 0, 0); }
            else       { zA = __builtin_amdgcn_mfma_f32_16x16x32_bf16(a, wz, zA, 0, 0, 0);
                         rA = __builtin_amdgcn_mfma_f32_16x16x32_bf16(a, wr, rA, 0, 0, 0); }
        }
        __builtin_amdgcn_sched_barrier(0);
        bar_wait(flags, lane, wave, 2 * t);   // h(t-1) published
        __builtin_amdgcn_sched_barrier(0);

        // ==== Phase 1 h-part: 16 coherent loads (this K-half), reused z+r ====
        {
            const short* Ah = hb + (mt + r15) * 1024 + kh * 512 + kk;
            bf16x8 fr[16];
#pragma unroll
            for (int i = 0; i < 16; ++i)
                asm volatile("global_load_dwordx4 %0, %1, off sc0 sc1"
                             : "=v"(fr[i]) : "v"(Ah + i * 32));
            asm volatile("s_waitcnt vmcnt(0)" ::: "memory");
            __builtin_amdgcn_sched_barrier(0);
#pragma unroll
            for (int i = 0; i < 16; ++i) {
                int bk = 64 + kh * 64 + i * 4 + q;
                bf16x8 wz = *(const bf16x8*)(w1z + (bk * 16 + r15) * 8);
                bf16x8 wr = *(const bf16x8*)(w1r + (bk * 16 + r15) * 8);
                if (i & 1) { zB = __builtin_amdgcn_mfma_f32_16x16x32_bf16(fr[i], wz, zB, 0, 0, 0);
                             rB = __builtin_amdgcn_mfma_f32_16x16x32_bf16(fr[i], wr, rB, 0, 0, 0); }
                else       { zA = __builtin_amdgcn_mfma_f32_16x16x32_bf16(fr[i], wz, zA, 0, 0, 0);
                             rA = __builtin_amdgcn_mfma_f32_16x16x32_bf16(fr[i], wr, rA, 0, 0, 0); }
            }
        }
        {
            f32x4 pz = zA + zB;
            f32x4 pr = rA + rB;
            if (!owner) { red[tile][0][lane] = pz; red[tile][1][lane] = pr; }
            __syncthreads();
            if (owner) {
                f32x4 oz = red[tile][0][lane];
                f32x4 orr = red[tile][1][lane];
#pragma unroll
                for (int v = 0; v < 4; ++v) {
                    zreg[v] = sigmoidf_fast(pz[v] + oz[v] + biasZ);
                    float rv = sigmoidf_fast(pr[v] + orr[v] + biasR);
                    store_coh_u16(sb + (mb + v) * 1024 + jcol,
                                  float_to_bf16bits(rv * hreg[v]));  // fp32 h
                }
            }
        }
        bar_arrive(flags, g, 2 * t + 1);

        // ==== Phase 2 x-part (candidate, this K-half), pre-wait ====
        f32x4 cA = {0.f,0.f,0.f,0.f}, cB = {0.f,0.f,0.f,0.f};
#pragma unroll
        for (int i = 0; i < 8; ++i) {
            bf16x8 a = *(const bf16x8*)(AxW + i * 32);
            int bk = kh * 32 + i * 4 + q;
            bf16x8 wc = *(const bf16x8*)(w2c + (bk * 16 + r15) * 8);
            if (i & 1) cB = __builtin_amdgcn_mfma_f32_16x16x32_bf16(a, wc, cB, 0, 0, 0);
            else       cA = __builtin_amdgcn_mfma_f32_16x16x32_bf16(a, wc, cA, 0, 0, 0);
        }
        __builtin_amdgcn_sched_barrier(0);
        bar_wait(flags, lane, wave, 2 * t + 1);  // s published
        __builtin_amdgcn_sched_barrier(0);

        // ==== Phase 2 s-part + reduce + blend ====
        {
            const short* As = sb + (mt + r15) * 1024 + kh * 512 + kk;
            bf16x8 fs[16];
#pragma unroll
            for (int i = 0; i < 16; ++i)
                asm volatile("global_load_dwordx4 %0, %1, off sc0 sc1"
                             : "=v"(fs[i]) : "v"(As + i * 32));
            asm volatile("s_waitcnt vmcnt(0)" ::: "memory");
            __builtin_amdgcn_sched_barrier(0);
#pragma unroll
            for (int i = 0; i < 16; ++i) {
                int bk = 64 + kh * 64 + i * 4 + q;
                bf16x8 wc = *(const bf16x8*)(w2c + (bk * 16 + r15) * 8);
                if (i & 1) cB = __builtin_amdgcn_mfma_f32_16x16x32_bf16(fs[i], wc, cB, 0, 0, 0);
                else       cA = __builtin_amdgcn_mfma_f32_16x16x32_bf16(fs[i], wc, cA, 0, 0, 0);
            }
            f32x4 pc = cA + cB;
            if (!owner) red[tile][0][lane] = pc;
            __syncthreads();
            if (owner) {
                f32x4 oc = red[tile][0][lane];
#pragma unroll
                for (int v = 0; v < 4; ++v) {
                    float cv = tanhf(pc[v] + oc[v] + biasC);
                    float h_new = (1.0f - zreg[v]) * hreg[v] + zreg[v] * cv;
                    hreg[v] = h_new;
                    store_coh_u16(hb + (mb + v) * 1024 + jcol,
                                  float_to_bf16bits(h_new));
                }
            }
        }
        bar_arrive(flags, g, 2 * t + 2);

        // deferred HBM output stores — off the synchronization critical path
        if (owner) {
            float* outt = out + (long long)t * 64 * 1024;
#pragma unroll
            for (int v = 0; v < 4; ++v)
                outt[(mb + v) * 1024 + jcol] = hreg[v];
        }
    }
}

extern "C" void kernel_launch(void* const* d_in, const int* in_sizes, int n_in,
                              void* d_out, int out_size, void* d_ws, size_t ws_size,
                              hipStream_t stream)
{
    (void)in_sizes; (void)n_in; (void)out_size; (void)ws_size;
    const float* x  = (const float*)d_in[0];
    const float* h0 = (const float*)d_in[1];
    const float* Wz = (const float*)d_in[2];
    const float* bz = (const float*)d_in[3];
    const float* Wr = (const float*)d_in[4];
    const float* br = (const float*)d_in[5];
    const float* Wc = (const float*)d_in[6];
    const float* bc = (const float*)d_in[7];
    float* out = (float*)d_out;

    // ws layout (bytes, 256-aligned): total ~43.3 MB
    char* ws = (char*)d_ws;
    __hip_bfloat16* Wzr = (__hip_bfloat16*)(ws);              // [2048][1536] bf16
    __hip_bfloat16* Wcb = (__hip_bfloat16*)(ws + 6291456);    // [1024][1536] bf16
    __hip_bfloat16* xb  = (__hip_bfloat16*)(ws + 9437184);    // [512][64][512] bf16
    __hip_bfloat16* hb  = (__hip_bfloat16*)(ws + 42991616);   // [64][1024] bf16
    __hip_bfloat16* sb  = (__hip_bfloat16*)(ws + 43122688);   // [64][1024] bf16
    unsigned*    flags  = (unsigned*)(ws + 43253760);         // 128 x 128B

    k_convert_weights<<<1024, 256, 0, stream>>>(Wz, Wr, Wc, Wzr, Wcb);
    k_convert_x<<<2048, 256, 0, stream>>>(x, xb);
    k_init_h<<<256, 256, 0, stream>>>(h0, hb);
    (void)hipMemsetAsync(flags, 0, NWG * 32 * sizeof(unsigned), stream);

    k_gru_persistent<<<NWG, 256, 0, stream>>>(
        xb, h0, hb, Wzr, Wcb, bz, br, bc, sb, out, flags);
}